// Round 5
// baseline (462.630 us; speedup 1.0000x reference)
//
#include <hip/hip_runtime.h>
#include <hip/hip_bf16.h>
#include <stdint.h>

typedef __attribute__((ext_vector_type(8)))  short    short8;
typedef __attribute__((ext_vector_type(16))) float    floatx16;
typedef __attribute__((ext_vector_type(4)))  float    floatx4;
typedef __attribute__((ext_vector_type(4)))  uint32_t uint4v;

#define B_    64
#define CIN   64
#define COUT  128
#define T_    300
#define V_    25
#define NRED  (B_ * T_ * V_)     // 480000 elements per channel
#define NT    12                 // pass2: t's per block
#define NTC1  5                  // pass1: t-chunks -> grid (5, 64), 60 t / block
#define NT1   (T_ / NTC1)
#define MSLOTS 16
#define MSTRIDE 3200             // T00@0 T01@1024 T11@2048 qsum@3072 (3136 used)
#define EPS   1e-5f

__device__ __forceinline__ uint32_t pk2(float a, float b) {
    union { __hip_bfloat162 h; uint32_t u; } c;
    c.h = __float22bfloat162_rn(make_float2(a, b));
    return c.u;
}

__device__ __forceinline__ floatx16 fzero16() {
    floatx16 z;
#pragma unroll
    for (int i = 0; i < 16; ++i) z[i] = 0.f;
    return z;
}

// magic division by 25, valid for 0 <= n < 2048
__device__ __forceinline__ int div25(int n) { return (n * 5243) >> 17; }

// C-layout -> A/B-fragment layout via lane^32 half-wave swap (verified R2/R3).
__device__ __forceinline__ void cvt_hb(const floatx16 h, int q, short8 hb[2]) {
    uint32_t pk[8], pp[8];
#pragma unroll
    for (int i = 0; i < 8; ++i) pk[i] = pk2(h[2 * i], h[2 * i + 1]);
#pragma unroll
    for (int i = 0; i < 8; ++i) pp[i] = (uint32_t)__shfl_xor((int)pk[i], 32, 64);
#pragma unroll
    for (int s = 0; s < 2; ++s) {
        union { short8 sv; uint32_t u[4]; } F;
        F.u[0] = q ? pp[4 * s + 2] : pk[4 * s];
        F.u[1] = q ? pp[4 * s + 3] : pk[4 * s + 1];
        F.u[2] = q ? pk[4 * s + 2] : pp[4 * s];
        F.u[3] = q ? pk[4 * s + 3] : pp[4 * s + 1];
        hb[s] = F.sv;
    }
}

// adjᵀ frag (verified R3): af[s] [row=w=ln][k=v=16s+8q+j] = adj[v][w], zero-pad.
__device__ __forceinline__ void build_af(const float* __restrict__ adj,
                                         int ln, int q, short8 af[2]) {
#pragma unroll
    for (int s = 0; s < 2; ++s) {
        union { short8 sv; uint32_t u[4]; } F;
#pragma unroll
        for (int p = 0; p < 4; ++p) {
            int v0 = 16 * s + 8 * q + 2 * p;
            float e0 = (v0     < V_ && ln < V_) ? adj[v0 * V_ + ln]       : 0.f;
            float e1 = (v0 + 1 < V_ && ln < V_) ? adj[(v0 + 1) * V_ + ln] : 0.f;
            F.u[p] = pk2(e0, e1);
        }
        af[s] = F.sv;
    }
}

//  wf[kk]: Wᵀ B-frag  B[k=c=16kk+8q+j][n=o=32*wave+ln] = W[o][c]
__device__ __forceinline__ void build_wf(const float* __restrict__ W,
                                         int wave, int ln, int q, short8 wf[4]) {
    const float* wr = W + (32 * wave + ln) * CIN;
#pragma unroll
    for (int kk = 0; kk < 4; ++kk) {
        int c0 = 16 * kk + 8 * q;
        floatx4 a = *(const floatx4*)(wr + c0);
        floatx4 b = *(const floatx4*)(wr + c0 + 4);
        union { short8 sv; uint32_t u[4]; } F;
        F.u[0] = pk2(a[0], a[1]); F.u[1] = pk2(a[2], a[3]);
        F.u[2] = pk2(b[0], b[1]); F.u[3] = pk2(b[2], b[3]);
        wf[kk] = F.sv;
    }
}

// ============================ PASS 1 (Gram stats) ===========================
// c-major f32 staging, 4 t's: float buf[(c*4+tl)*32 + swizzled-v].
// 16B-granule XOR swizzle: granule g stored at g ^ (c&7). v>=25 zero-padded.
__device__ __forceinline__ void stage1_issue(const float* __restrict__ xb, int t4,
                                             int tid, floatx4 st[7]) {
#pragma unroll
    for (int i = 0; i < 7; ++i) {
        int cid = i * 256 + tid;
        if (i < 6 || tid < 64) {
            int c = div25(cid), ch = cid - 25 * c;
            st[i] = *(const floatx4*)(xb + c * 7500 + t4 * 25 + 4 * ch);
        }
    }
}

__device__ __forceinline__ void stage1_commit(float* __restrict__ buf, int tid,
                                              const floatx4 st[7]) {
#pragma unroll
    for (int i = 0; i < 7; ++i) {
        int cid = i * 256 + tid;
        if (i < 6 || tid < 64) {
            int c = div25(cid), ch = cid - 25 * c;
#pragma unroll
            for (int k = 0; k < 4; ++k) {
                int tv = 4 * ch + k;
                int tl = div25(tv);
                int v  = tv - 25 * tl;
                buf[(c * 4 + tl) * 32 + (((v >> 2) ^ (c & 7)) << 2) + (v & 3)] =
                    st[i][k];
            }
        }
    }
}

// Grid (5, 64), block 256 = 4 waves; wave w owns t-slot w of each 4-t stage.
// Per t: Qᵀ = mfma(af, X-Bfrag) (4 MFMA), cvt, M(3 sym tiles) += QQᵀ (6 MFMA).
__global__ __launch_bounds__(256, 2) void pass1_kernel(
    const float* __restrict__ x, const float* __restrict__ adj,
    float* __restrict__ wsM)
{
    __shared__ __attribute__((aligned(16))) float ldsx[2][8192];

    const int tid  = threadIdx.x;
    const int wave = tid >> 6;
    const int lane = tid & 63;
    const int q    = lane >> 5;
    const int ln   = lane & 31;
    const int b    = blockIdx.y;
    const int tbase = blockIdx.x * NT1;

    short8 af[2];
    build_af(adj, ln, q, af);
    const float* xb = x + (size_t)b * (CIN * T_ * V_);

    // zero the v=25..31 pad of both buffers (af zero-pad kills them in MFMA,
    // but LDS garbage could be NaN: 0*NaN = NaN)
    for (int k = tid; k < 2 * 256 * 7; k += 256) {
        int v   = 25 + (k % 7);
        int row = (k / 7) & 255;
        int bf  = k / (7 * 256);
        int c   = row >> 2;
        ldsx[bf][row * 32 + (((v >> 2) ^ (c & 7)) << 2) + (v & 3)] = 0.f;
    }

    floatx4 st[7];
    stage1_issue(xb, tbase, tid, st);
    stage1_commit(&ldsx[0][0], tid, st);
    __syncthreads();
    int cur = 0;

    floatx16 M00 = fzero16(), M01 = fzero16(), M11 = fzero16();
    float qs0 = 0.f, qs1 = 0.f;
    const int x7 = ln & 7;

    for (int g = 0; g < NT1 / 4; ++g) {
        if (g < NT1 / 4 - 1) stage1_issue(xb, tbase + 4 * (g + 1), tid, st);
        __builtin_amdgcn_sched_barrier(0);   // keep next-tile loads above compute

        const float* bufp = &ldsx[cur][0];
        // X B-frags for this wave's t-slot: [k=v=16s+8q+j][n=c=32cT+ln]
        short8 xf0[2], xf1[2];
#pragma unroll
        for (int s = 0; s < 2; ++s) {
            const int gb = 4 * s + 2 * q;
#pragma unroll
            for (int cT = 0; cT < 2; ++cT) {
                const float* row = bufp + ((32 * cT + ln) * 4 + wave) * 32;
                floatx4 u  = *(const floatx4*)(row + ((gb ^ x7) << 2));
                floatx4 v4 = *(const floatx4*)(row + (((gb + 1) ^ x7) << 2));
                union { short8 sv; uint32_t uu[4]; } F;
                F.uu[0] = pk2(u[0], u[1]);  F.uu[1] = pk2(u[2], u[3]);
                F.uu[2] = pk2(v4[0], v4[1]); F.uu[3] = pk2(v4[2], v4[3]);
                if (cT == 0) xf0[s] = F.sv; else xf1[s] = F.sv;
            }
        }
        // Qᵀ[w][c] = Σ_v adjᵀ[w][v]·Xᵀ[v][c]   (D: lane=c, regs=w-rows)
        floatx16 qt0 = fzero16(), qt1 = fzero16();
        qt0 = __builtin_amdgcn_mfma_f32_32x32x16_bf16(af[0], xf0[0], qt0, 0, 0, 0);
        qt0 = __builtin_amdgcn_mfma_f32_32x32x16_bf16(af[1], xf0[1], qt0, 0, 0, 0);
        qt1 = __builtin_amdgcn_mfma_f32_32x32x16_bf16(af[0], xf1[0], qt1, 0, 0, 0);
        qt1 = __builtin_amdgcn_mfma_f32_32x32x16_bf16(af[1], xf1[1], qt1, 0, 0, 0);
#pragma unroll
        for (int r = 0; r < 16; ++r) { qs0 += qt0[r]; qs1 += qt1[r]; }
        // Q as A/B-frag (identical layouts, verified R1): [k=w] halves
        short8 qb0[2], qb1[2];
        cvt_hb(qt0, q, qb0);
        cvt_hb(qt1, q, qb1);
#pragma unroll
        for (int s = 0; s < 2; ++s) {
            M00 = __builtin_amdgcn_mfma_f32_32x32x16_bf16(qb0[s], qb0[s], M00, 0, 0, 0);
            M01 = __builtin_amdgcn_mfma_f32_32x32x16_bf16(qb0[s], qb1[s], M01, 0, 0, 0);
            M11 = __builtin_amdgcn_mfma_f32_32x32x16_bf16(qb1[s], qb1[s], M11, 0, 0, 0);
        }

        if (g < NT1 / 4 - 1) {
            stage1_commit(&ldsx[cur ^ 1][0], tid, st);
            __syncthreads();
            cur ^= 1;
        }
    }

    // flush partials: lanes l and l^32 of Qᵀ share c, hold different w-rows
    qs0 += __shfl_xor(qs0, 32, 64);
    qs1 += __shfl_xor(qs1, 32, 64);
    const int slot = (blockIdx.y * NTC1 + blockIdx.x) & (MSLOTS - 1);
    float* mb = wsM + slot * MSTRIDE;
#pragma unroll
    for (int r = 0; r < 16; ++r) {
        const int crow = (r & 3) + 8 * (r >> 2) + 4 * q;
        atomicAdd(&mb[       crow * 32 + ln], M00[r]);
        atomicAdd(&mb[1024 + crow * 32 + ln], M01[r]);
        atomicAdd(&mb[2048 + crow * 32 + ln], M11[r]);
    }
    if (q == 0) {
        atomicAdd(&mb[3072 + ln],      qs0);
        atomicAdd(&mb[3072 + 32 + ln], qs1);
    }
}

// ==================== tiny stats kernel: (M,qsum) -> (sc,sh) ================
__global__ __launch_bounds__(256) void stats_kernel(
    const float* __restrict__ W, const float* __restrict__ gamma,
    const float* __restrict__ beta, const float* __restrict__ wsM,
    float* __restrict__ wsStats)
{
    __shared__ float Ms[3136];
    __shared__ float red[256];
    const int tid = threadIdx.x;
    for (int e = tid; e < 3136; e += 256) {
        float a = 0.f;
#pragma unroll
        for (int s = 0; s < MSLOTS; ++s) a += wsM[s * MSTRIDE + e];
        Ms[e] = a;
    }
    __syncthreads();

    const int o = tid & 127;
    const int h = tid >> 7;          // wave-uniform (waves 0,1 -> h=0; 2,3 -> 1)
    float wrow[64];
#pragma unroll
    for (int c = 0; c < 64; ++c) wrow[c] = W[o * 64 + c];

    float ss = 0.f;
    if (h == 0) {
#pragma unroll
        for (int ci = 0; ci < 32; ++ci) {      // c = ci < 32
            float inner = 0.f;
#pragma unroll
            for (int cp = 0; cp < 32; ++cp)
                inner += Ms[ci * 32 + cp] * wrow[cp]
                       + Ms[1024 + ci * 32 + cp] * wrow[32 + cp];
            ss += wrow[ci] * inner;
        }
    } else {
#pragma unroll
        for (int ci = 0; ci < 32; ++ci) {      // c = 32 + ci
            float inner = 0.f;
#pragma unroll
            for (int cp = 0; cp < 32; ++cp)
                inner += Ms[1024 + cp * 32 + ci] * wrow[cp]     // T01ᵀ
                       + Ms[2048 + ci * 32 + cp] * wrow[32 + cp];
            ss += wrow[32 + ci] * inner;
        }
    }
    red[tid] = ss;
    __syncthreads();
    if (tid < 128) {
        const float sst = red[tid] + red[tid + 128];
        float S = 0.f;
#pragma unroll
        for (int c = 0; c < 64; ++c) S += wrow[c] * Ms[3072 + c];
        const float mean = S / (float)NRED;
        const float var  = sst / (float)NRED - mean * mean;
        const float inv  = rsqrtf(var + EPS);
        const float sc   = gamma[o] * inv;
        wsStats[o]       = sc;
        wsStats[128 + o] = beta[o] - mean * sc;
    }
}

// ============================ PASS 2 (R4, table prologue) ===================
__device__ __forceinline__ void stage_issue(const float* __restrict__ xb, int t4,
                                            int tid, floatx4 a[4], floatx4 b[4]) {
#pragma unroll
    for (int i = 0; i < 4; ++i) {
        int cid = i * 256 + tid;
        if (i < 3 || tid < 32) {
            int ch = cid >> 5;
            int cp = cid & 31;
            const float* p0 = xb + (2 * cp) * 7500 + t4 * 25 + 4 * ch;
            a[i] = *(const floatx4*)p0;
            b[i] = *(const floatx4*)(p0 + 7500);
        }
    }
}

__device__ __forceinline__ void stage_commit(uint32_t* __restrict__ lds, int tid,
                                             const floatx4 a[4], const floatx4 b[4]) {
#pragma unroll
    for (int i = 0; i < 4; ++i) {
        int cid = i * 256 + tid;
        if (i < 3 || tid < 32) {
            int ch = cid >> 5;
            int cp = cid & 31;
            const int g  = cp >> 2;
            const int c2 = cp & 3;
#pragma unroll
            for (int k = 0; k < 4; ++k) {
                int tv = 4 * ch + k;
                lds[tv * 32 + (((g ^ (tv & 7)) << 2) | c2)] = pk2(a[i][k], b[i][k]);
            }
        }
    }
}

__device__ __forceinline__ void build_xa_ldsT(const uint32_t* __restrict__ lds,
                                              int tloc, int vcl, int q, short8 xa[4]) {
    const int tv = tloc * 25 + vcl;
    const uint32_t* row = lds + tv * 32;
    const int x7 = tv & 7;
#pragma unroll
    for (int kk = 0; kk < 4; ++kk) {
        union { short8 sv; uint4v u4; } F;
        F.u4 = *(const uint4v*)(row + (((q + 2 * kk) ^ x7) << 2));
        xa[kk] = F.sv;
    }
}

__device__ __forceinline__ floatx16 compute_yt(const short8 xa[4], const short8 wf[4],
                                               const short8 af[2], int q) {
    floatx16 h = fzero16();
#pragma unroll
    for (int kk = 0; kk < 4; ++kk)
        h = __builtin_amdgcn_mfma_f32_32x32x16_bf16(xa[kk], wf[kk], h, 0, 0, 0);
    short8 hb[2];
    cvt_hb(h, q, hb);
    floatx16 y = fzero16();
#pragma unroll
    for (int s = 0; s < 2; ++s)
        y = __builtin_amdgcn_mfma_f32_32x32x16_bf16(af[s], hb[s], y, 0, 0, 0);
    return y;
}

__global__ __launch_bounds__(256, 2) void pass2_kernel(
    const float* __restrict__ x, const float* __restrict__ adj,
    const float* __restrict__ W,
    const float* __restrict__ wsStats,
    float* __restrict__ out)
{
    __shared__ __attribute__((aligned(16))) uint32_t bufA[3200];
    __shared__ __attribute__((aligned(16))) uint32_t bufB[3200];
    __shared__ __attribute__((aligned(16))) float ldso[4][3200];

    const int tid  = threadIdx.x;
    const int wave = tid >> 6;
    const int lane = tid & 63;
    const int q    = lane >> 5;
    const int ln   = lane & 31;
    const int b    = blockIdx.y;
    const int tbase = blockIdx.x * NT;
    const int o_l  = 32 * wave + ln;

    short8 wf[4], af[2];
    build_wf(W, wave, ln, q, wf);
    build_af(adj, ln, q, af);

    const float sc = wsStats[o_l];
    const float sh = wsStats[128 + o_l];

    const int vcl = ln < V_ ? ln : V_ - 1;
    const float* xb = x + (size_t)b * (CIN * T_ * V_);
    float* const ob = out + (size_t)(b * COUT + 32 * wave) * (T_ * V_);

    floatx4 sa[4], sb[4];
    stage_issue(xb, tbase, tid, sa, sb);
    stage_commit(bufA, tid, sa, sb);
    __syncthreads();
    uint32_t* cur = bufA;
    uint32_t* nxt = bufB;

    for (int g = 0; g < NT / 4; ++g) {
        const int t4 = tbase + 4 * g;
        if (g < NT / 4 - 1) stage_issue(xb, tbase + 4 * (g + 1), tid, sa, sb);
        __builtin_amdgcn_sched_barrier(0);   // keep next-tile loads above compute

        float* const ow0 = &ldso[wave][ln * 100];
#pragma unroll
        for (int tloc = 0; tloc < 4; ++tloc) {
            short8 xa[4];
            build_xa_ldsT(cur, tloc, vcl, q, xa);
            floatx16 y = compute_yt(xa, wf, af, q);
            float* ow = ow0 + tloc * 25 + 4 * q;
#pragma unroll
            for (int g2 = 0; g2 < 3; ++g2) {
#pragma unroll
                for (int j = 0; j < 4; ++j) {
                    float v = sc * y[4 * g2 + j] + sh;
                    ow[8 * g2 + j] = v > 0.f ? v : 0.f;
                }
            }
            if (q == 0) {                      // w = 24  (reg 12)
                float v = sc * y[12] + sh;
                ow0[tloc * 25 + 24] = v > 0.f ? v : 0.f;
            }
        }

        if (g < NT / 4 - 1) {
            stage_commit(nxt, tid, sa, sb);
            __syncthreads();
        }

        // flush this wave's 32o x 100 floats: 13 coalesced 16B-aligned dwordx4
#pragma unroll
        for (int f = 0; f < 13; ++f) {
            int cid = f * 64 + lane;
            if (f < 12 || lane < 32) {
                int o = div25(cid);
                int c = cid - 25 * o;
                floatx4 v = *(const floatx4*)&ldso[wave][o * 100 + 4 * c];
                *(floatx4*)(ob + (size_t)o * (T_ * V_) + t4 * 25 + 4 * c) = v;
            }
        }

        uint32_t* t = cur; cur = nxt; nxt = t;
    }
}

// ============================================================================
extern "C" void kernel_launch(void* const* d_in, const int* in_sizes, int n_in,
                              void* d_out, int out_size, void* d_ws, size_t ws_size,
                              hipStream_t stream) {
    const float* x     = (const float*)d_in[0];
    const float* adj   = (const float*)d_in[1];
    const float* W     = (const float*)d_in[2];
    // d_in[3] = conv bias: cancelled exactly by training-mode BatchNorm -> unused
    const float* gamma = (const float*)d_in[4];
    const float* beta  = (const float*)d_in[5];
    float* out = (float*)d_out;

    float* wsM     = (float*)d_ws;
    float* wsStats = wsM + MSLOTS * MSTRIDE;

    hipMemsetAsync(wsM, 0, MSLOTS * MSTRIDE * sizeof(float), stream);

    pass1_kernel<<<dim3(NTC1, B_), 256, 0, stream>>>(x, adj, wsM);
    stats_kernel<<<dim3(1), 256, 0, stream>>>(W, gamma, beta, wsM, wsStats);
    pass2_kernel<<<dim3(T_ / NT, B_), 256, 0, stream>>>(x, adj, W, wsStats, out);
}